// Round 16
// baseline (115.754 us; speedup 1.0000x reference)
//
#include <hip/hip_runtime.h>
#include <hip/hip_bf16.h>

#define CDIM 4096
#define DDIM 1024
#define BDIM 16384
#define EDIAG 2.7182818284590452f
#define QBASE 0.36787944f          // e^-1
#define QSCALE 0.15669957f         // (e - e^-1)/15
#define QINV 6.3816357f            // 1/QSCALE

using frag_ab = __attribute__((ext_vector_type(8))) short;   // 8 bf16 (4 VGPRs)
using frag_cd = __attribute__((ext_vector_type(4))) float;   // 4 fp32
using f32x4   = __attribute__((ext_vector_type(4))) float;   // native vec for nt-load

typedef __attribute__((address_space(1))) const void gvoid;
typedef __attribute__((address_space(3))) void lvoid;

__device__ __forceinline__ float block_sum(float v, float* red) {
  int t = threadIdx.x;
  #pragma unroll
  for (int off = 32; off; off >>= 1) v += __shfl_xor(v, off);
  __syncthreads();
  if ((t & 63) == 0) red[t >> 6] = v;
  __syncthreads();
  return (red[0] + red[1]) + (red[2] + red[3]);
}

__device__ __forceinline__ unsigned short f2bfbits(float f) {
  __hip_bfloat16 b = __float2bfloat16(f);
  return *(unsigned short*)&b;
}

// 4-bit linear quant of e-values (e in [e^-1, e])
__device__ __forceinline__ int q4(float ex) {
  int q = __float2int_rn((ex - QBASE) * QINV);
  return min(15, max(0, q));
}

// ---- Kernel A: wn = bf16( weight_row / max(||row||, 1e-8) ); zero Sf ----
__global__ __launch_bounds__(256) void k_norm(const float* __restrict__ w,
                                              __hip_bfloat16* __restrict__ wnb,
                                              float* __restrict__ Sf) {
  __shared__ float red[4];
  __shared__ float s_inv;
  int row = blockIdx.x, t = threadIdx.x;
  const float4* wr = (const float4*)(w + (size_t)row * DDIM);
  float4 x = wr[t];
  float ss = (x.x * x.x + x.y * x.y) + (x.z * x.z + x.w * x.w);
  ss = block_sum(ss, red);
  if (t == 0) {
    s_inv = 1.0f / fmaxf(sqrtf(ss), 1e-8f);
    Sf[row] = 0.0f;
  }
  __syncthreads();
  float inv = s_inv;
  ushort4 o;
  o.x = f2bfbits(x.x * inv);
  o.y = f2bfbits(x.y * inv);
  o.z = f2bfbits(x.z * inv);
  o.w = f2bfbits(x.w * inv);
  *(ushort4*)(wnb + (size_t)row * DDIM + t * 4) = o;
}

// ---- Kernel B: e4 = u4(exp(wn @ wn^T)), FULL matrix, 256x256 tile ----
// 8 waves (2Mx4N, 128x64 out/wave, acc[8][4]), BK=64, 128KB LDS dbuf.
// 4-phase K-tile schedule, counted vmcnt (never 0 in steady state):
//   stage order per K-tile: B0,B1,B2,B3,A0,A2,A1,A3 (2 issues/phase, post-barrier)
//   p0: vmcnt(2)+bar (forces kt's B*,A0,A2; 4-phase lead)  -> quad(hm0,hn0)
//   p1: (no bar)                                            -> quad(hm0,hn1)
//   p2: vmcnt(4)+bar (forces kt's A1,A3; 3-phase lead)      -> quad(hm1,hn0)
//   p3: (no bar)                                            -> quad(hm1,hn1)
// T2 XOR swizzle (pre-swizzled gload src + swizzled ds_read), T5 setprio,
// T1 bijective XCD swizzle (256 = 8 x 32).
__global__ __launch_bounds__(512) void k_simexp(const __hip_bfloat16* __restrict__ wb,
                                                unsigned char* __restrict__ e4,
                                                float* __restrict__ Sf) {
  __shared__ char smem[131072];                // 2 bufs x (A 32KB | B 32KB)
  int tid = threadIdx.x;
  int lane = tid & 63, wid = tid >> 6;
  int l15 = lane & 15, lk = (lane >> 4) * 8;
  int wm = wid >> 2, wn4 = wid & 3;            // 2M x 4N waves

  int swz = (blockIdx.x & 7) * 32 + (blockIdx.x >> 3);   // T1 XCD chunking
  int brow = swz >> 4, bcol = swz & 15;

  int srow = tid >> 3;
  int swzel = ((tid & 7) ^ (srow & 7)) * 8;    // pre-swizzled global chunk
  const __hip_bfloat16* gA0 = wb + (size_t)(brow * 256 +   0 + srow) * DDIM + swzel;
  const __hip_bfloat16* gA1 = wb + (size_t)(brow * 256 +  64 + srow) * DDIM + swzel;
  const __hip_bfloat16* gA2 = wb + (size_t)(brow * 256 + 128 + srow) * DDIM + swzel;
  const __hip_bfloat16* gA3 = wb + (size_t)(brow * 256 + 192 + srow) * DDIM + swzel;
  const __hip_bfloat16* gB0 = wb + (size_t)(bcol * 256 +   0 + srow) * DDIM + swzel;
  const __hip_bfloat16* gB1 = wb + (size_t)(bcol * 256 +  64 + srow) * DDIM + swzel;
  const __hip_bfloat16* gB2 = wb + (size_t)(bcol * 256 + 128 + srow) * DDIM + swzel;
  const __hip_bfloat16* gB3 = wb + (size_t)(bcol * 256 + 192 + srow) * DDIM + swzel;
  int ldst = tid * 16;

#define SA(buf, s, gp, k0) __builtin_amdgcn_global_load_lds((gvoid*)((gp) + (k0)), \
    (lvoid*)(smem + (buf) + (s) * 8192 + ldst), 16, 0, 0)
#define SB(buf, s, gp, k0) __builtin_amdgcn_global_load_lds((gvoid*)((gp) + (k0)), \
    (lvoid*)(smem + (buf) + 32768 + (s) * 8192 + ldst), 16, 0, 0)

  int xorb = (l15 & 7) << 4;
  frag_cd acc[8][4] = {};

  // prologue: K-tile 0 -> buf0, exact order B0,B1,B2,B3,A0,A2,A1,A3
  SB(0, 0, gB0, 0); SB(0, 1, gB1, 0); SB(0, 2, gB2, 0); SB(0, 3, gB3, 0);
  SA(0, 0, gA0, 0); SA(0, 2, gA2, 0); SA(0, 1, gA1, 0); SA(0, 3, gA3, 0);

  for (int kt = 0; kt < 16; kt++) {
    int c  = (kt & 1) * 65536;
    int nx = 65536 - c;
    int k1 = (kt + 1) * 64;
    const char* bA0 = smem + c + (2 * wm) * 8192;        // hm=0 segment
    const char* bA1 = bA0 + 8192;                        // hm=1 segment
    const char* bB  = smem + c + 32768 + wn4 * 8192;

    frag_ab a[4][2], b[2][2];

    // ---------------- phase 0: quad(hm0, hn0) ----------------
    asm volatile("s_waitcnt vmcnt(2)" ::: "memory");
    __builtin_amdgcn_sched_barrier(0);
    __builtin_amdgcn_s_barrier();
    __builtin_amdgcn_sched_barrier(0);
    if (kt < 15) { SB(nx, 0, gB0, k1); SB(nx, 1, gB1, k1); }
    #pragma unroll
    for (int ks = 0; ks < 2; ks++) {
      int off = ((ks * 32 + lk) * 2) ^ xorb;
      #pragma unroll
      for (int mm = 0; mm < 4; mm++)
        a[mm][ks] = *(const frag_ab*)(const void*)(bA0 + (mm * 16 + l15) * 128 + off);
      #pragma unroll
      for (int nn = 0; nn < 2; nn++)
        b[nn][ks] = *(const frag_ab*)(const void*)(bB + (nn * 16 + l15) * 128 + off);
    }
    __builtin_amdgcn_s_setprio(1);
    #pragma unroll
    for (int mm = 0; mm < 4; mm++)
      #pragma unroll
      for (int nn = 0; nn < 2; nn++)
        #pragma unroll
        for (int ks = 0; ks < 2; ks++)
          acc[mm][nn] = __builtin_amdgcn_mfma_f32_16x16x32_bf16(a[mm][ks], b[nn][ks], acc[mm][nn], 0, 0, 0);
    __builtin_amdgcn_s_setprio(0);

    // ---------------- phase 1: quad(hm0, hn1), reuse a ----------------
    if (kt < 15) { SB(nx, 2, gB2, k1); SB(nx, 3, gB3, k1); }
    #pragma unroll
    for (int ks = 0; ks < 2; ks++) {
      int off = ((ks * 32 + lk) * 2) ^ xorb;
      #pragma unroll
      for (int nn = 0; nn < 2; nn++)
        b[nn][ks] = *(const frag_ab*)(const void*)(bB + (32 + nn * 16 + l15) * 128 + off);
    }
    __builtin_amdgcn_s_setprio(1);
    #pragma unroll
    for (int mm = 0; mm < 4; mm++)
      #pragma unroll
      for (int nn = 0; nn < 2; nn++)
        #pragma unroll
        for (int ks = 0; ks < 2; ks++)
          acc[mm][2 + nn] = __builtin_amdgcn_mfma_f32_16x16x32_bf16(a[mm][ks], b[nn][ks], acc[mm][2 + nn], 0, 0, 0);
    __builtin_amdgcn_s_setprio(0);

    // ---------------- phase 2: quad(hm1, hn0) ----------------
    if (kt < 15) { asm volatile("s_waitcnt vmcnt(4)" ::: "memory"); }
    else         { asm volatile("s_waitcnt vmcnt(0)" ::: "memory"); }
    __builtin_amdgcn_sched_barrier(0);
    __builtin_amdgcn_s_barrier();
    __builtin_amdgcn_sched_barrier(0);
    if (kt < 15) { SA(nx, 0, gA0, k1); SA(nx, 2, gA2, k1); }
    #pragma unroll
    for (int ks = 0; ks < 2; ks++) {
      int off = ((ks * 32 + lk) * 2) ^ xorb;
      #pragma unroll
      for (int mm = 0; mm < 4; mm++)
        a[mm][ks] = *(const frag_ab*)(const void*)(bA1 + (mm * 16 + l15) * 128 + off);
      #pragma unroll
      for (int nn = 0; nn < 2; nn++)
        b[nn][ks] = *(const frag_ab*)(const void*)(bB + (nn * 16 + l15) * 128 + off);
    }
    __builtin_amdgcn_s_setprio(1);
    #pragma unroll
    for (int mm = 0; mm < 4; mm++)
      #pragma unroll
      for (int nn = 0; nn < 2; nn++)
        #pragma unroll
        for (int ks = 0; ks < 2; ks++)
          acc[4 + mm][nn] = __builtin_amdgcn_mfma_f32_16x16x32_bf16(a[mm][ks], b[nn][ks], acc[4 + mm][nn], 0, 0, 0);
    __builtin_amdgcn_s_setprio(0);

    // ---------------- phase 3: quad(hm1, hn1), reuse a ----------------
    if (kt < 15) { SA(nx, 1, gA1, k1); SA(nx, 3, gA3, k1); }
    #pragma unroll
    for (int ks = 0; ks < 2; ks++) {
      int off = ((ks * 32 + lk) * 2) ^ xorb;
      #pragma unroll
      for (int nn = 0; nn < 2; nn++)
        b[nn][ks] = *(const frag_ab*)(const void*)(bB + (32 + nn * 16 + l15) * 128 + off);
    }
    __builtin_amdgcn_s_setprio(1);
    #pragma unroll
    for (int mm = 0; mm < 4; mm++)
      #pragma unroll
      for (int nn = 0; nn < 2; nn++)
        #pragma unroll
        for (int ks = 0; ks < 2; ks++)
          acc[4 + mm][2 + nn] = __builtin_amdgcn_mfma_f32_16x16x32_bf16(a[mm][ks], b[nn][ks], acc[4 + mm][2 + nn], 0, 0, 0);
    __builtin_amdgcn_s_setprio(0);
  }
#undef SA
#undef SB

  // ---- epilogue: exp, u4 pack (column pairs via shfl), row-sum atomics ----
  int rg = (lane >> 4) * 4;
  int r0g = brow * 256 + wm * 128;
  int c0g = bcol * 256 + wn4 * 64 + l15;

  #pragma unroll
  for (int m8 = 0; m8 < 8; m8++)
    #pragma unroll
    for (int j = 0; j < 4; j++) {
      int rglob = r0g + m8 * 16 + rg + j;
      float rsum = 0.f;
      #pragma unroll
      for (int n4 = 0; n4 < 4; n4++) {
        float ex = __expf(acc[m8][n4][j]);
        rsum += ex;
        int q = q4(ex);
        int qr = __shfl_xor(q, 1);
        if (!(l15 & 1))
          e4[(size_t)rglob * 2048 + (unsigned)((c0g + n4 * 16) >> 1)] =
              (unsigned char)(q | (qr << 4));
      }
      rsum += __shfl_xor(rsum, 1);
      rsum += __shfl_xor(rsum, 2);
      rsum += __shfl_xor(rsum, 4);
      rsum += __shfl_xor(rsum, 8);
      if (l15 == 0) atomicAdd(&Sf[rglob], rsum);
    }
}

// ---- Kernel C: per-sample loss (R15 config, frozen) ----
__global__ __launch_bounds__(256) void k_loss(const float* __restrict__ pred,
                                              const int* __restrict__ tgt,
                                              const unsigned char* __restrict__ e4,
                                              const float* __restrict__ Sf,
                                              float* __restrict__ part) {
  __shared__ uint2 erow[256];                  // 2048 B = one e4 row
  __shared__ float reds[4], redq[4], redp[4];
  int i = blockIdx.x, t = threadIdx.x;
  int tg = tgt[i];
  erow[t] = ((const uint2*)(e4 + (size_t)tg * 2048))[t];
  const f32x4* pr = (const f32x4*)(pred + (size_t)i * CDIM);
  __syncthreads();
  const unsigned short* er = (const unsigned short*)erow;

  float se = 0.f, sp = 0.f, qd = 0.f;
  #pragma unroll
  for (int j = 0; j < 4; j++) {
    f32x4 v = __builtin_nontemporal_load(pr + t + j * 256);
    unsigned int u = er[t + j * 256];
    se += (__expf(v[0]) + __expf(v[1])) + (__expf(v[2]) + __expf(v[3]));
    sp += (v[0] + v[1]) + (v[2] + v[3]);
    qd += (float)(u & 15u) * v[0] +
          (float)((u >> 4) & 15u) * v[1] +
          (float)((u >> 8) & 15u) * v[2] +
          (float)(u >> 12) * v[3];
  }
  #pragma unroll
  for (int off = 32; off; off >>= 1) {
    se += __shfl_xor(se, off);
    sp += __shfl_xor(sp, off);
    qd += __shfl_xor(qd, off);
  }
  if ((t & 63) == 0) { reds[t >> 6] = se; redq[t >> 6] = qd; redp[t >> 6] = sp; }
  __syncthreads();
  if (t == 0) {
    se = (reds[0] + reds[1]) + (reds[2] + reds[3]);
    qd = (redq[0] + redq[1]) + (redq[2] + redq[3]);
    sp = (redp[0] + redp[1]) + (redp[2] + redp[3]);
    float dot = QSCALE * qd + QBASE * sp;
    float lse = __logf(se);
    float pt = pred[(size_t)i * CDIM + tg];
    float ce = lse - pt;
    float S = Sf[tg];
    float t2 = (S * lse - dot - EDIAG * ce) / (S - EDIAG);
    part[i] = 0.9f * ce + 0.1f * t2;
  }
}

// ---- Kernel D: deterministic final reduce ----
__global__ __launch_bounds__(256) void k_final(const float* __restrict__ part,
                                               float* __restrict__ out) {
  __shared__ float red[4];
  int t = threadIdx.x;
  float s = 0.f;
  for (int i = t; i < BDIM; i += 256) s += part[i];
  s = block_sum(s, red);
  if (t == 0) out[0] = s * (1.0f / BDIM);
}

extern "C" void kernel_launch(void* const* d_in, const int* in_sizes, int n_in,
                              void* d_out, int out_size, void* d_ws, size_t ws_size,
                              hipStream_t stream) {
  const float* pred = (const float*)d_in[0];
  const float* weight = (const float*)d_in[1];
  const int* target = (const int*)d_in[2];
  float* out = (float*)d_out;
  char* ws = (char*)d_ws;

  __hip_bfloat16* wnb = (__hip_bfloat16*)ws;                          // 8 MB
  unsigned char* e4 = (unsigned char*)(ws + (size_t)(8u << 20));      // 8 MB (u4-packed)
  float* Sf   = (float*)(ws + (size_t)(16u << 20));                   // 16 KB
  float* part = (float*)(ws + (size_t)(16u << 20) + 16384);           // 64 KB

  k_norm<<<dim3(CDIM), dim3(256), 0, stream>>>(weight, wnb, Sf);
  k_simexp<<<dim3(256), dim3(512), 0, stream>>>(wnb, e4, Sf);
  k_loss<<<dim3(BDIM), dim3(256), 0, stream>>>(pred, target, e4, Sf, part);
  k_final<<<dim3(1), dim3(256), 0, stream>>>(part, out);
}